// Round 1
// baseline (1437.873 us; speedup 1.0000x reference)
//
#include <hip/hip_runtime.h>
#include <hip/hip_bf16.h>

typedef unsigned short u16;
typedef unsigned int u32;
typedef float f32x4 __attribute__((ext_vector_type(4)));
typedef short bf16x8 __attribute__((ext_vector_type(8)));

#define INV_SQRT32 0.17677669529663688f

// ---------------------------------------------------------------------------
// Stage 1: per-32-group Hadamard rotate (FWHT, Sylvester order) + MXFP4
// quant-dequant, output bf16 (exact representation of deq values).
// One thread per 32-element group; groups are contiguous in memory since
// K % 32 == 0 and rows are row-major.
// ---------------------------------------------------------------------------
__global__ __launch_bounds__(256) void rotquant_kernel(
    const float* __restrict__ T, u16* __restrict__ Q, int ngroups)
{
    int g = blockIdx.x * 256 + threadIdx.x;
    if (g >= ngroups) return;

    const float4* src = (const float4*)(T + (size_t)g * 32);
    float v[32];
#pragma unroll
    for (int i = 0; i < 8; ++i) {
        float4 t = src[i];
        v[i*4+0] = t.x; v[i*4+1] = t.y; v[i*4+2] = t.z; v[i*4+3] = t.w;
    }

    // FWHT: result[k] = sum_h (-1)^popcount(h&k) v[h]  == Sylvester H (unscaled)
#pragma unroll
    for (int s = 1; s < 32; s <<= 1) {
#pragma unroll
        for (int i = 0; i < 32; ++i) {
            if (!(i & s)) {
                float a = v[i], b = v[i | s];
                v[i] = a + b;
                v[i | s] = a - b;
            }
        }
    }

    float amax = 0.f;
#pragma unroll
    for (int i = 0; i < 32; ++i) {
        v[i] *= INV_SQRT32;                 // fold H's 32^-0.5
        amax = fmaxf(amax, fabsf(v[i]));
    }

    u32 ab = __float_as_uint(amax);
    int be = (int)(ab >> 23);               // biased exponent (sign bit is 0)
    u16 q16[32];
    if (be >= 3) {
        // e = floor(log2(amax)) - 2 = be - 129 ; scale = 2^e (exact)
        float scale  = __uint_as_float((u32)(be - 2) << 23);   // 2^(be-129)
        float iscale = __uint_as_float((u32)(256 - be) << 23); // 2^(129-be)
#pragma unroll
        for (int i = 0; i < 32; ++i) {
            float a = v[i] * iscale;        // exact (power-of-2)
            float m = fminf(fabsf(a), 6.0f);
            // np.digitize(mids=[.25,.75,1.25,1.75,2.5,3.5,5]) tie-goes-up
            float q = (m < 0.25f) ? 0.0f :
                      (m < 0.75f) ? 0.5f :
                      (m < 1.25f) ? 1.0f :
                      (m < 1.75f) ? 1.5f :
                      (m < 2.5f)  ? 2.0f :
                      (m < 3.5f)  ? 3.0f :
                      (m < 5.0f)  ? 4.0f : 6.0f;
            float d = copysignf(q, a) * scale;   // exact in bf16
            q16[i] = (u16)(__float_as_uint(d) >> 16);  // exact truncation
        }
    } else {
        // amax below 2^-124 (never hits with this data): emit zeros
#pragma unroll
        for (int i = 0; i < 32; ++i) q16[i] = 0;
    }

    uint4* dst = (uint4*)(Q + (size_t)g * 32);
#pragma unroll
    for (int c = 0; c < 4; ++c) {
        uint4 p;
        p.x = (u32)q16[c*8+0] | ((u32)q16[c*8+1] << 16);
        p.y = (u32)q16[c*8+2] | ((u32)q16[c*8+3] << 16);
        p.z = (u32)q16[c*8+4] | ((u32)q16[c*8+5] << 16);
        p.w = (u32)q16[c*8+6] | ((u32)q16[c*8+7] << 16);
        dst[c] = p;
    }
}

// ---------------------------------------------------------------------------
// Stage 2: C[M,N] = A[M,K] * B[N,K]^T + bias (all row-major, A/B bf16, C fp32)
// m97 structure: 128x128 tile, BK=64, 4 waves (2x2), 16x16x32 bf16 MFMA,
// global_load_lds width 16, 2-barrier K-loop, XCD-aware block swizzle.
// ---------------------------------------------------------------------------
__device__ __forceinline__ void gload16(const void* g, void* l)
{
    __builtin_amdgcn_global_load_lds(
        (__attribute__((address_space(1))) void*)g,
        (__attribute__((address_space(3))) void*)l, 16, 0, 0);
}

__device__ __forceinline__ void mfma_bf16(f32x4& c, bf16x8 a, bf16x8 b)
{
    asm("v_mfma_f32_16x16x32_bf16 %0, %1, %2, %0"
        : "+v"(c) : "v"(a), "v"(b));
}

__global__ __launch_bounds__(256) void gemm_bt_bias(
    const u16* __restrict__ A, const u16* __restrict__ B,
    const float* __restrict__ bias, float* __restrict__ C,
    int M, int N, int K)
{
    __shared__ u16 smem[16384];   // A tile [128][64] at 0, B tile [128][64] at 8192

    const int tid  = threadIdx.x;
    const int wave = tid >> 6;
    const int lane = tid & 63;
    const int lr   = lane & 15;   // frag row/col index
    const int lk   = lane >> 4;   // frag k-group
    const int wm   = wave >> 1;   // wave grid 2x2
    const int wn   = wave & 1;

    // XCD-aware bijective swizzle (nwg % 8 == 0 here)
    int nwg = gridDim.x;
    int cpx = nwg >> 3;
    int bid = blockIdx.x;
    int wg  = (bid & 7) * cpx + (bid >> 3);
    int nbn = N >> 7;
    int bn  = wg % nbn;
    int bm  = wg / nbn;

    f32x4 acc[4][4];
#pragma unroll
    for (int i = 0; i < 4; ++i)
#pragma unroll
        for (int j = 0; j < 4; ++j) {
            f32x4 z = {0.f, 0.f, 0.f, 0.f};
            acc[i][j] = z;
        }

    const size_t lda = (size_t)K;

    for (int kt = 0; kt < K; kt += 64) {
        // ---- stage A tile: 16KB = 4 rounds x (4 waves x 64 lanes x 16B)
#pragma unroll
        for (int j = 0; j < 4; ++j) {
            int lo  = j * 4096 + wave * 1024;     // wave-uniform LDS byte base
            int o   = lo + lane * 16;             // this lane's linear byte slot
            int row = o >> 7;                     // LDS row (128B per row)
            int ce  = (o & 127) >> 1;             // col in elements
            gload16(A + (size_t)(bm * 128 + row) * lda + kt + ce,
                    (char*)smem + lo);
        }
        // ---- stage B tile
#pragma unroll
        for (int j = 0; j < 4; ++j) {
            int o   = j * 4096 + wave * 1024 + lane * 16;
            int lo  = 16384 + j * 4096 + wave * 1024;
            int row = o >> 7;
            int ce  = (o & 127) >> 1;
            gload16(B + (size_t)(bn * 128 + row) * lda + kt + ce,
                    (char*)smem + lo);
        }
        __syncthreads();   // drains vmcnt (global_load_lds) + barrier

#pragma unroll
        for (int ks = 0; ks < 2; ++ks) {
            bf16x8 av[4], bv[4];
#pragma unroll
            for (int mi = 0; mi < 4; ++mi)
                av[mi] = *(const bf16x8*)(smem + (wm*64 + mi*16 + lr) * 64 + ks*32 + lk*8);
#pragma unroll
            for (int ni = 0; ni < 4; ++ni)
                bv[ni] = *(const bf16x8*)(smem + 8192 + (wn*64 + ni*16 + lr) * 64 + ks*32 + lk*8);
#pragma unroll
            for (int mi = 0; mi < 4; ++mi)
#pragma unroll
                for (int ni = 0; ni < 4; ++ni)
                    mfma_bf16(acc[mi][ni], av[mi], bv[ni]);
        }
        __syncthreads();
    }

    // Epilogue: C/D layout col = lane&15, row = (lane>>4)*4 + reg
    const int cb = bn * 128 + wn * 64;
    const int rb = bm * 128 + wm * 64;
#pragma unroll
    for (int ni = 0; ni < 4; ++ni) {
        float bb = bias[cb + ni * 16 + lr];
#pragma unroll
        for (int mi = 0; mi < 4; ++mi) {
#pragma unroll
            for (int j = 0; j < 4; ++j) {
                int r = rb + mi * 16 + lk * 4 + j;
                C[(size_t)r * N + cb + ni * 16 + lr] = acc[mi][ni][j] + bb;
            }
        }
    }
}

// ---------------------------------------------------------------------------
extern "C" void kernel_launch(void* const* d_in, const int* in_sizes, int n_in,
                              void* d_out, int out_size, void* d_ws, size_t ws_size,
                              hipStream_t stream)
{
    const float* x    = (const float*)d_in[0];   // [B*S, K] = [8192, 4096]
    const float* w    = (const float*)d_in[1];   // [O, K]   = [16384, 4096]
    const float* bias = (const float*)d_in[2];   // [O]
    // d_in[3] (fwd_hadamard) is Sylvester H * 32^-0.5 — computed via FWHT.

    const int O = in_sizes[2];            // 16384
    const int K = in_sizes[1] / O;        // 4096
    const int M = in_sizes[0] / K;        // 8192

    u16* xq = (u16*)d_ws;                 // [M, K] bf16 : 67 MB
    u16* wq = xq + (size_t)M * K;         // [O, K] bf16 : 134 MB (ws total 201 MB)

    const int gx = M * (K / 32);
    const int gw = O * (K / 32);
    rotquant_kernel<<<(gx + 255) / 256, 256, 0, stream>>>(x, xq, gx);
    rotquant_kernel<<<(gw + 255) / 256, 256, 0, stream>>>(w, wq, gw);

    dim3 grid((M / 128) * (O / 128));     // 8192 blocks, % 8 == 0
    gemm_bt_bias<<<grid, 256, 0, stream>>>(xq, wq, bias, (float*)d_out, M, O, K);
}

// Round 2
// 916.950 us; speedup vs baseline: 1.5681x; 1.5681x over previous
//
#include <hip/hip_runtime.h>

typedef unsigned short u16;
typedef unsigned int u32;
typedef unsigned char u8;
typedef int v8i __attribute__((ext_vector_type(8)));
typedef int v4i __attribute__((ext_vector_type(4)));
typedef float v16f __attribute__((ext_vector_type(16)));

#define INV_SQRT32 0.17677669529663688f

// ---------------------------------------------------------------------------
// Stage 1: per-32-group FWHT (Sylvester Hadamard) + MXFP4 quantize.
// Output: packed E2M1 nibbles (even elem = low nibble, OCP order) + E8M0
// scale byte per group. One thread per 32-element group.
// ---------------------------------------------------------------------------
__global__ __launch_bounds__(256) void rotquant4_kernel(
    const float* __restrict__ T, u8* __restrict__ Q4, u8* __restrict__ S,
    int ngroups)
{
    int g = blockIdx.x * 256 + threadIdx.x;
    if (g >= ngroups) return;

    const float4* src = (const float4*)(T + (size_t)g * 32);
    float v[32];
#pragma unroll
    for (int i = 0; i < 8; ++i) {
        float4 t = src[i];
        v[i*4+0] = t.x; v[i*4+1] = t.y; v[i*4+2] = t.z; v[i*4+3] = t.w;
    }

    // FWHT == Sylvester H (unscaled); fold 32^-0.5 afterwards
#pragma unroll
    for (int s = 1; s < 32; s <<= 1) {
#pragma unroll
        for (int i = 0; i < 32; ++i) {
            if (!(i & s)) {
                float a = v[i], b = v[i | s];
                v[i] = a + b;
                v[i | s] = a - b;
            }
        }
    }

    float amax = 0.f;
#pragma unroll
    for (int i = 0; i < 32; ++i) {
        v[i] *= INV_SQRT32;
        amax = fmaxf(amax, fabsf(v[i]));
    }

    u32 ab = __float_as_uint(amax);
    int be = (int)(ab >> 23);               // biased exponent of amax
    u32 w[4] = {0u, 0u, 0u, 0u};
    u8 sbyte = 0;
    if (be >= 3) {
        // scale = 2^(be-129); E8M0 byte = (be-129)+127 = be-2
        sbyte = (u8)(be - 2);
        float iscale = __uint_as_float((u32)(256 - be) << 23); // 2^(129-be), exact
#pragma unroll
        for (int i = 0; i < 32; ++i) {
            float a = v[i] * iscale;        // exact (power-of-2 multiply)
            float m = fminf(fabsf(a), 6.0f);
            // np.digitize midpoints [.25,.75,1.25,1.75,2.5,3.5,5], tie-goes-up
            int c = (m < 0.25f) ? 0 :
                    (m < 0.75f) ? 1 :
                    (m < 1.25f) ? 2 :
                    (m < 1.75f) ? 3 :
                    (m < 2.5f)  ? 4 :
                    (m < 3.5f)  ? 5 :
                    (m < 5.0f)  ? 6 : 7;
            c |= (int)((__float_as_uint(a) >> 28) & 8u);   // sign -> bit 3
            w[i >> 3] |= (u32)c << (4 * (i & 7));
        }
    }
    // else: amax < 2^-124 (never with this data) -> all-zero codes, scale 2^-127

    uint4 p; p.x = w[0]; p.y = w[1]; p.z = w[2]; p.w = w[3];
    *(uint4*)(Q4 + (size_t)g * 16) = p;
    S[g] = sbyte;
}

// ---------------------------------------------------------------------------
// Stage 2: C[M,N] = deq(A) * deq(B)^T + bias via MX-scaled FP4 MFMA.
// 128x128 tile, BK=128, 4 waves (2x2), mfma_scale_f32_32x32x64_f8f6f4,
// single-buffer 2-barrier loop (m97 skeleton), global_load_lds width 16/4.
// LDS data layout [kblock][row][16B] via pre-swizzled global source so the
// fragment ds_read_b128 is 4-way (not 16-way) bank aliased.
// ---------------------------------------------------------------------------
__device__ __forceinline__ void gload16(const void* g, void* l)
{
    __builtin_amdgcn_global_load_lds(
        (__attribute__((address_space(1))) void*)g,
        (__attribute__((address_space(3))) void*)l, 16, 0, 0);
}
__device__ __forceinline__ void gload4(const void* g, void* l)
{
    __builtin_amdgcn_global_load_lds(
        (__attribute__((address_space(1))) void*)g,
        (__attribute__((address_space(3))) void*)l, 4, 0, 0);
}

__global__ __launch_bounds__(256) void gemm4_bias(
    const u8* __restrict__ A4, const u8* __restrict__ AS,
    const u8* __restrict__ B4, const u8* __restrict__ BS,
    const float* __restrict__ bias, float* __restrict__ C,
    int M, int N, int K)
{
    // A: [4 kblk][128 row][16B] @0     (8 KB)
    // B: same                  @8192   (8 KB)
    // A scales [128 row][4B]   @16384  (512 B)
    // B scales [128 row][4B]   @16896  (512 B)
    __shared__ __align__(16) u8 smem[17408];

    const int tid  = threadIdx.x;
    const int wave = tid >> 6;
    const int lane = tid & 63;
    const int l31  = lane & 31;
    const int lhi  = lane >> 5;
    const int wm   = wave >> 1;
    const int wn   = wave & 1;

    // XCD-aware bijective swizzle (nwg = 8192, % 8 == 0)
    int nwg = gridDim.x;
    int cpx = nwg >> 3;
    int bid = blockIdx.x;
    int wg  = (bid & 7) * cpx + (bid >> 3);
    int nbn = N >> 7;
    int bn  = wg % nbn;
    int bm  = wg / nbn;

    const int Kb = K >> 1;    // packed bytes per row
    const int Ks = K >> 5;    // scale bytes per row

    v16f acc[2][2];
#pragma unroll
    for (int i = 0; i < 2; ++i)
#pragma unroll
        for (int j = 0; j < 2; ++j)
#pragma unroll
            for (int r = 0; r < 16; ++r) acc[i][j][r] = 0.f;

    const int sc_half = wave & 1;               // which 64-row half of scales
    const u8* sc_src  = (wave < 2)
        ? AS + (size_t)(bm * 128 + sc_half * 64 + lane) * Ks
        : BS + (size_t)(bn * 128 + sc_half * 64 + lane) * Ks;
    u8* sc_dst = smem + ((wave < 2) ? 16384 : 16896) + sc_half * 256;

    for (int kt = 0; kt < K; kt += 128) {
        // ---- stage A tile: 8KB = 2 rounds x (4 waves x 64 lanes x 16B)
#pragma unroll
        for (int j = 0; j < 2; ++j) {
            int lo  = j * 4096 + wave * 1024;   // wave-uniform LDS byte base
            int o   = lo + lane * 16;
            int blk = o >> 11;                  // k-block (0..3)
            int row = (o >> 4) & 127;
            gload16(A4 + (size_t)(bm * 128 + row) * Kb + (kt >> 1) + blk * 16,
                    smem + lo);
        }
        // ---- stage B tile
#pragma unroll
        for (int j = 0; j < 2; ++j) {
            int lo  = j * 4096 + wave * 1024;
            int o   = lo + lane * 16;
            int blk = o >> 11;
            int row = (o >> 4) & 127;
            gload16(B4 + (size_t)(bn * 128 + row) * Kb + (kt >> 1) + blk * 16,
                    smem + 8192 + lo);
        }
        // ---- stage scales (waves 0-1: A, waves 2-3: B; 64 rows x 4B each)
        gload4(sc_src + (kt >> 5), sc_dst);

        __syncthreads();   // drains vmcnt + barrier

        const u32* Asc = (const u32*)(smem + 16384);
        const u32* Bsc = (const u32*)(smem + 16896);
        u32 sa32[2], sb32[2];
#pragma unroll
        for (int mi = 0; mi < 2; ++mi) sa32[mi] = Asc[wm * 64 + mi * 32 + l31];
#pragma unroll
        for (int ni = 0; ni < 2; ++ni) sb32[ni] = Bsc[wn * 64 + ni * 32 + l31];

#pragma unroll
        for (int ks = 0; ks < 2; ++ks) {
            const int sh = (ks * 2 + lhi) * 8;  // scale byte select for this frag
            v8i a[2], b[2];
#pragma unroll
            for (int mi = 0; mi < 2; ++mi) {
                v4i t = *(const v4i*)(smem + (ks * 2 + lhi) * 2048
                                      + (wm * 64 + mi * 32 + l31) * 16);
                a[mi][0] = t[0]; a[mi][1] = t[1]; a[mi][2] = t[2]; a[mi][3] = t[3];
                a[mi][4] = 0; a[mi][5] = 0; a[mi][6] = 0; a[mi][7] = 0;
            }
#pragma unroll
            for (int ni = 0; ni < 2; ++ni) {
                v4i t = *(const v4i*)(smem + 8192 + (ks * 2 + lhi) * 2048
                                      + (wn * 64 + ni * 32 + l31) * 16);
                b[ni][0] = t[0]; b[ni][1] = t[1]; b[ni][2] = t[2]; b[ni][3] = t[3];
                b[ni][4] = 0; b[ni][5] = 0; b[ni][6] = 0; b[ni][7] = 0;
            }
#pragma unroll
            for (int mi = 0; mi < 2; ++mi) {
                int sA = (int)((sa32[mi] >> sh) & 0xffu);
#pragma unroll
                for (int ni = 0; ni < 2; ++ni) {
                    int sB = (int)((sb32[ni] >> sh) & 0xffu);
                    // cbsz=4 (FP4 E2M1) for A, blgp=4 for B, opsel=0 (byte 0)
                    acc[mi][ni] = __builtin_amdgcn_mfma_scale_f32_32x32x64_f8f6f4(
                        a[mi], b[ni], acc[mi][ni], 4, 4, 0, sA, 0, sB);
                }
            }
        }
        __syncthreads();
    }

    // Epilogue: 32x32 C/D layout: col = lane&31, row = (reg&3)+8*(reg>>2)+4*(lane>>5)
    const int cb = bn * 128 + wn * 64;
    const int rb = bm * 128 + wm * 64;
#pragma unroll
    for (int ni = 0; ni < 2; ++ni) {
        float bb = bias[cb + ni * 32 + l31];
#pragma unroll
        for (int mi = 0; mi < 2; ++mi) {
#pragma unroll
            for (int reg = 0; reg < 16; ++reg) {
                int row = (reg & 3) + 8 * (reg >> 2) + 4 * lhi;
                C[(size_t)(rb + mi * 32 + row) * N + cb + ni * 32 + l31]
                    = acc[mi][ni][reg] + bb;
            }
        }
    }
}

// ---------------------------------------------------------------------------
extern "C" void kernel_launch(void* const* d_in, const int* in_sizes, int n_in,
                              void* d_out, int out_size, void* d_ws, size_t ws_size,
                              hipStream_t stream)
{
    const float* x    = (const float*)d_in[0];   // [M, K] = [8192, 4096]
    const float* w    = (const float*)d_in[1];   // [O, K] = [16384, 4096]
    const float* bias = (const float*)d_in[2];   // [O]

    const int O = in_sizes[2];            // 16384
    const int K = in_sizes[1] / O;        // 4096
    const int M = in_sizes[0] / K;        // 8192

    u8* x4 = (u8*)d_ws;                           // [M, K/2]  : 16.8 MB
    u8* w4 = x4 + (size_t)M * (K / 2);            // [O, K/2]  : 33.6 MB
    u8* xs = w4 + (size_t)O * (K / 2);            // [M, K/32] : 1 MB
    u8* ws = xs + (size_t)M * (K / 32);           // [O, K/32] : 2 MB

    const int gx = M * (K / 32);
    const int gw = O * (K / 32);
    rotquant4_kernel<<<(gx + 255) / 256, 256, 0, stream>>>(x, x4, xs, gx);
    rotquant4_kernel<<<(gw + 255) / 256, 256, 0, stream>>>(w, w4, ws, gw);

    dim3 grid((M / 128) * (O / 128));     // 8192 blocks, % 8 == 0
    gemm4_bias<<<grid, 256, 0, stream>>>(x4, xs, w4, ws, bias, (float*)d_out,
                                         M, O, K);
}

// Round 3
// 851.064 us; speedup vs baseline: 1.6895x; 1.0774x over previous
//
#include <hip/hip_runtime.h>

typedef unsigned short u16;
typedef unsigned int u32;
typedef unsigned char u8;
typedef int v8i __attribute__((ext_vector_type(8)));
typedef int v4i __attribute__((ext_vector_type(4)));
typedef float v16f __attribute__((ext_vector_type(16)));

#define INV_SQRT32 0.17677669529663688f

// ---------------------------------------------------------------------------
// Stage 1: per-32-group FWHT (Sylvester Hadamard) + MXFP4 quantize.
// Output: packed E2M1 nibbles (even elem = low nibble) + E8M0 scale byte.
// ---------------------------------------------------------------------------
__global__ __launch_bounds__(256) void rotquant4_kernel(
    const float* __restrict__ T, u8* __restrict__ Q4, u8* __restrict__ S,
    int ngroups)
{
    int g = blockIdx.x * 256 + threadIdx.x;
    if (g >= ngroups) return;

    const float4* src = (const float4*)(T + (size_t)g * 32);
    float v[32];
#pragma unroll
    for (int i = 0; i < 8; ++i) {
        float4 t = src[i];
        v[i*4+0] = t.x; v[i*4+1] = t.y; v[i*4+2] = t.z; v[i*4+3] = t.w;
    }

#pragma unroll
    for (int s = 1; s < 32; s <<= 1) {
#pragma unroll
        for (int i = 0; i < 32; ++i) {
            if (!(i & s)) {
                float a = v[i], b = v[i | s];
                v[i] = a + b;
                v[i | s] = a - b;
            }
        }
    }

    float amax = 0.f;
#pragma unroll
    for (int i = 0; i < 32; ++i) {
        v[i] *= INV_SQRT32;
        amax = fmaxf(amax, fabsf(v[i]));
    }

    u32 ab = __float_as_uint(amax);
    int be = (int)(ab >> 23);
    u32 w[4] = {0u, 0u, 0u, 0u};
    u8 sbyte = 0;
    if (be >= 3) {
        sbyte = (u8)(be - 2);               // E8M0 of 2^(be-129)
        float iscale = __uint_as_float((u32)(256 - be) << 23); // 2^(129-be)
#pragma unroll
        for (int i = 0; i < 32; ++i) {
            float a = v[i] * iscale;        // exact
            float m = fminf(fabsf(a), 6.0f);
            int c = (m < 0.25f) ? 0 :
                    (m < 0.75f) ? 1 :
                    (m < 1.25f) ? 2 :
                    (m < 1.75f) ? 3 :
                    (m < 2.5f)  ? 4 :
                    (m < 3.5f)  ? 5 :
                    (m < 5.0f)  ? 6 : 7;
            c |= (int)((__float_as_uint(a) >> 28) & 8u);
            w[i >> 3] |= (u32)c << (4 * (i & 7));
        }
    }

    uint4 p; p.x = w[0]; p.y = w[1]; p.z = w[2]; p.w = w[3];
    *(uint4*)(Q4 + (size_t)g * 16) = p;
    S[g] = sbyte;
}

// ---------------------------------------------------------------------------
// Stage 2: C = deq(A) * deq(B)^T + bias via MX-scaled FP4 MFMA.
// 128x128 tile, BK=128, 4 waves, double-buffered LDS (T3-min 2-phase:
// stage t+1 before compute t, one __syncthreads per iter), 4 blocks/CU,
// XCD-chunked + L2-grouped block ordering.
// ---------------------------------------------------------------------------
__device__ __forceinline__ void gload16(const void* g, void* l)
{
    __builtin_amdgcn_global_load_lds(
        (__attribute__((address_space(1))) void*)g,
        (__attribute__((address_space(3))) void*)l, 16, 0, 0);
}
__device__ __forceinline__ void gload4(const void* g, void* l)
{
    __builtin_amdgcn_global_load_lds(
        (__attribute__((address_space(1))) void*)g,
        (__attribute__((address_space(3))) void*)l, 4, 0, 0);
}

#define BUF_BYTES 17408   // A 8KB | B 8KB | Asc 512B | Bsc 512B

__global__ __launch_bounds__(256, 4) void gemm4_bias(
    const u8* __restrict__ A4, const u8* __restrict__ AS,
    const u8* __restrict__ B4, const u8* __restrict__ BS,
    const float* __restrict__ bias, float* __restrict__ C,
    int M, int N, int K)
{
    __shared__ __align__(16) u8 smem[2 * BUF_BYTES];   // 34 KB -> 4 blocks/CU

    const int tid  = threadIdx.x;
    const int wave = tid >> 6;
    const int lane = tid & 63;
    const int l31  = lane & 31;
    const int lhi  = lane >> 5;
    const int wm   = wave >> 1;
    const int wn   = wave & 1;

    // --- block ordering: XCD-chunked, then 8-bm-deep grouped walk within
    // each chunk so the live working set (8 A-panels + 1 B-panel ~ 2.3 MB)
    // fits the 4 MB per-XCD L2.
    const int nbn = N >> 7;
    const int nbm = M >> 7;
    int nwg = gridDim.x;
    int bid = blockIdx.x;
    int bm, bn;
    if ((nwg & 7) == 0 && (nbm & 7) == 0) {
        int cpx = nwg >> 3;
        int wg  = (bid & 7) * cpx + (bid >> 3);     // XCD-chunked
        int bpc = nbm >> 3;                          // bm-rows per chunk
        int c   = wg / cpx;
        int r   = wg - c * cpx;
        bm = c * bpc + (r & 7);
        bn = r >> 3;
    } else {
        bn = bid % nbn;
        bm = bid / nbn;
    }

    const int Kb = K >> 1;    // packed bytes per row
    const int Ks = K >> 5;    // scale bytes per row

    v16f acc[2][2];
#pragma unroll
    for (int i = 0; i < 2; ++i)
#pragma unroll
        for (int j = 0; j < 2; ++j)
#pragma unroll
            for (int r = 0; r < 16; ++r) acc[i][j][r] = 0.f;

    const int sc_half = wave & 1;
    const u8* sc_src  = (wave < 2)
        ? AS + (size_t)(bm * 128 + sc_half * 64 + lane) * Ks
        : BS + (size_t)(bn * 128 + sc_half * 64 + lane) * Ks;
    const int sc_dofs = ((wave < 2) ? 16384 : 16896) + sc_half * 256;

    const u8* Abase = A4 + (size_t)(bm * 128) * Kb;
    const u8* Bbase = B4 + (size_t)(bn * 128) * Kb;

    // staging geometry (region-local): rel = j*4096 + wave*1024 + lane*16
    const int rel0 = wave * 1024 + lane * 16;

#define STAGE(bufofs, kt)                                                     \
    do {                                                                      \
        _Pragma("unroll")                                                     \
        for (int j = 0; j < 2; ++j) {                                         \
            int rel = j * 4096 + rel0;                                        \
            int blk = rel >> 11;                                              \
            int row = (rel >> 4) & 127;                                       \
            gload16(Abase + (size_t)row * Kb + ((kt) >> 1) + blk * 16,        \
                    smem + (bufofs) + j * 4096 + wave * 1024);                \
        }                                                                     \
        _Pragma("unroll")                                                     \
        for (int j = 0; j < 2; ++j) {                                         \
            int rel = j * 4096 + rel0;                                        \
            int blk = rel >> 11;                                              \
            int row = (rel >> 4) & 127;                                       \
            gload16(Bbase + (size_t)row * Kb + ((kt) >> 1) + blk * 16,        \
                    smem + (bufofs) + 8192 + j * 4096 + wave * 1024);         \
        }                                                                     \
        gload4(sc_src + ((kt) >> 5), smem + (bufofs) + sc_dofs);              \
    } while (0)

    const int NT = K >> 7;    // 128-wide K tiles

    STAGE(0, 0);
    __syncthreads();          // drains vmcnt + barrier

    for (int t = 0; t < NT; ++t) {
        const int cofs = (t & 1) * BUF_BYTES;
        if (t + 1 < NT) {
            const int pofs = ((t + 1) & 1) * BUF_BYTES;
            STAGE(pofs, (t + 1) << 7);
        }

        const u32* Asc = (const u32*)(smem + cofs + 16384);
        const u32* Bsc = (const u32*)(smem + cofs + 16896);
        u32 sa32[2], sb32[2];
#pragma unroll
        for (int mi = 0; mi < 2; ++mi) sa32[mi] = Asc[wm * 64 + mi * 32 + l31];
#pragma unroll
        for (int ni = 0; ni < 2; ++ni) sb32[ni] = Bsc[wn * 64 + ni * 32 + l31];

#pragma unroll
        for (int ks = 0; ks < 2; ++ks) {
            const int sh = (ks * 2 + lhi) * 8;
            v8i a[2], b[2];
#pragma unroll
            for (int mi = 0; mi < 2; ++mi) {
                v4i v = *(const v4i*)(smem + cofs + (ks * 2 + lhi) * 2048
                                      + (wm * 64 + mi * 32 + l31) * 16);
                a[mi][0] = v[0]; a[mi][1] = v[1]; a[mi][2] = v[2]; a[mi][3] = v[3];
                a[mi][4] = 0; a[mi][5] = 0; a[mi][6] = 0; a[mi][7] = 0;
            }
#pragma unroll
            for (int ni = 0; ni < 2; ++ni) {
                v4i v = *(const v4i*)(smem + cofs + 8192 + (ks * 2 + lhi) * 2048
                                      + (wn * 64 + ni * 32 + l31) * 16);
                b[ni][0] = v[0]; b[ni][1] = v[1]; b[ni][2] = v[2]; b[ni][3] = v[3];
                b[ni][4] = 0; b[ni][5] = 0; b[ni][6] = 0; b[ni][7] = 0;
            }
#pragma unroll
            for (int mi = 0; mi < 2; ++mi) {
                int sA = (int)((sa32[mi] >> sh) & 0xffu);
#pragma unroll
                for (int ni = 0; ni < 2; ++ni) {
                    int sB = (int)((sb32[ni] >> sh) & 0xffu);
                    acc[mi][ni] = __builtin_amdgcn_mfma_scale_f32_32x32x64_f8f6f4(
                        a[mi], b[ni], acc[mi][ni], 4, 4, 0, sA, 0, sB);
                }
            }
        }
        __syncthreads();      // drains this iter's prefetch + guards dbuf swap
    }

    // Epilogue: 32x32 C/D: col = lane&31, row = (reg&3)+8*(reg>>2)+4*(lane>>5)
    const int cb = bn * 128 + wn * 64;
    const int rb = bm * 128 + wm * 64;
#pragma unroll
    for (int ni = 0; ni < 2; ++ni) {
        float bb = bias[cb + ni * 32 + l31];
#pragma unroll
        for (int mi = 0; mi < 2; ++mi) {
#pragma unroll
            for (int reg = 0; reg < 16; ++reg) {
                int row = (reg & 3) + 8 * (reg >> 2) + 4 * lhi;
                C[(size_t)(rb + mi * 32 + row) * N + cb + ni * 32 + l31]
                    = acc[mi][ni][reg] + bb;
            }
        }
    }
#undef STAGE
}

// ---------------------------------------------------------------------------
extern "C" void kernel_launch(void* const* d_in, const int* in_sizes, int n_in,
                              void* d_out, int out_size, void* d_ws, size_t ws_size,
                              hipStream_t stream)
{
    const float* x    = (const float*)d_in[0];   // [M, K] = [8192, 4096]
    const float* w    = (const float*)d_in[1];   // [O, K] = [16384, 4096]
    const float* bias = (const float*)d_in[2];   // [O]

    const int O = in_sizes[2];            // 16384
    const int K = in_sizes[1] / O;        // 4096
    const int M = in_sizes[0] / K;        // 8192

    u8* x4 = (u8*)d_ws;                           // [M, K/2]
    u8* w4 = x4 + (size_t)M * (K / 2);            // [O, K/2]
    u8* xs = w4 + (size_t)O * (K / 2);            // [M, K/32]
    u8* ws = xs + (size_t)M * (K / 32);           // [O, K/32]

    const int gx = M * (K / 32);
    const int gw = O * (K / 32);
    rotquant4_kernel<<<(gx + 255) / 256, 256, 0, stream>>>(x, x4, xs, gx);
    rotquant4_kernel<<<(gw + 255) / 256, 256, 0, stream>>>(w, w4, ws, gw);

    dim3 grid((M / 128) * (O / 128));     // 8192 blocks
    gemm4_bias<<<grid, 256, 0, stream>>>(x4, xs, w4, ws, bias, (float*)d_out,
                                         M, O, K);
}

// Round 4
// 521.507 us; speedup vs baseline: 2.7572x; 1.6319x over previous
//
#include <hip/hip_runtime.h>

typedef unsigned short u16;
typedef unsigned int u32;
typedef unsigned char u8;
typedef int v8i __attribute__((ext_vector_type(8)));
typedef int v4i __attribute__((ext_vector_type(4)));
typedef float v16f __attribute__((ext_vector_type(16)));

#define INV_SQRT32 0.17677669529663688f

// ---------------------------------------------------------------------------
// Stage 1: per-32-group FWHT (Sylvester Hadamard) + MXFP4 quantize.
// Output is written PRE-TILED for the GEMM:
//   data  chunk16 for (row, kblock kb):  tile = (row>>7)*ntk + (kb>>2)
//         byte = tile*8192 + (kb&3)*2048 + (row&127)*16     (slot-major)
//   scale byte for (row, kb):  tile*512 + (row&127)*4 + (kb&3)
// so GEMM staging is fully linear/contiguous per K-tile.
// ---------------------------------------------------------------------------
__global__ __launch_bounds__(256) void rotquant4_kernel(
    const float* __restrict__ T, u8* __restrict__ Q4, u8* __restrict__ S,
    int ngroups, int gpr /* K/32 */, int ntk /* K/128 */)
{
    int g = blockIdx.x * 256 + threadIdx.x;
    if (g >= ngroups) return;

    int row = g / gpr;
    int kb  = g - row * gpr;

    const float4* src = (const float4*)(T + (size_t)g * 32);
    float v[32];
#pragma unroll
    for (int i = 0; i < 8; ++i) {
        float4 t = src[i];
        v[i*4+0] = t.x; v[i*4+1] = t.y; v[i*4+2] = t.z; v[i*4+3] = t.w;
    }

#pragma unroll
    for (int s = 1; s < 32; s <<= 1) {
#pragma unroll
        for (int i = 0; i < 32; ++i) {
            if (!(i & s)) {
                float a = v[i], b = v[i | s];
                v[i] = a + b;
                v[i | s] = a - b;
            }
        }
    }

    float amax = 0.f;
#pragma unroll
    for (int i = 0; i < 32; ++i) {
        v[i] *= INV_SQRT32;
        amax = fmaxf(amax, fabsf(v[i]));
    }

    u32 ab = __float_as_uint(amax);
    int be = (int)(ab >> 23);
    u32 w[4] = {0u, 0u, 0u, 0u};
    u8 sbyte = 0;
    if (be >= 3) {
        sbyte = (u8)(be - 2);               // E8M0 of 2^(be-129)
        float iscale = __uint_as_float((u32)(256 - be) << 23); // 2^(129-be)
#pragma unroll
        for (int i = 0; i < 32; ++i) {
            float a = v[i] * iscale;        // exact
            float m = fminf(fabsf(a), 6.0f);
            int c = (m < 0.25f) ? 0 :
                    (m < 0.75f) ? 1 :
                    (m < 1.25f) ? 2 :
                    (m < 1.75f) ? 3 :
                    (m < 2.5f)  ? 4 :
                    (m < 3.5f)  ? 5 :
                    (m < 5.0f)  ? 6 : 7;
            c |= (int)((__float_as_uint(a) >> 28) & 8u);
            w[i >> 3] |= (u32)c << (4 * (i & 7));
        }
    }

    size_t tile = (size_t)(row >> 7) * (size_t)ntk + (size_t)(kb >> 2);
    uint4 p; p.x = w[0]; p.y = w[1]; p.z = w[2]; p.w = w[3];
    *(uint4*)(Q4 + tile * 8192 + (size_t)(kb & 3) * 2048
              + (size_t)(row & 127) * 16) = p;
    S[tile * 512 + (size_t)(row & 127) * 4 + (kb & 3)] = sbyte;
}

// ---------------------------------------------------------------------------
// Stage 2: C = deq(A) * deq(B)^T + bias via MX-scaled FP4 MFMA.
// 128x128 tile, BK=128, 4 waves. T3+T4 minimum 2-phase: double-buffered LDS,
// raw s_barrier + counted s_waitcnt vmcnt(5) (prefetch stays in flight across
// the barrier; drain-0 only in the peeled last iteration). Staging is fully
// linear gload16 from the pre-tiled operand layout; fragment ds_read_b128 has
// the contiguous-read bank profile (lane -> bank-group = lane&7).
// ---------------------------------------------------------------------------
__device__ __forceinline__ void gload16(const void* g, void* l)
{
    __builtin_amdgcn_global_load_lds(
        (__attribute__((address_space(1))) void*)g,
        (__attribute__((address_space(3))) void*)l, 16, 0, 0);
}
__device__ __forceinline__ void gload4(const void* g, void* l)
{
    __builtin_amdgcn_global_load_lds(
        (__attribute__((address_space(1))) void*)g,
        (__attribute__((address_space(3))) void*)l, 4, 0, 0);
}

#define BUF_BYTES 17408   // A 8KB | B 8KB | Asc 512B | Bsc 512B

__global__ __launch_bounds__(256, 4) void gemm4_bias(
    const u8* __restrict__ A4, const u8* __restrict__ AS,
    const u8* __restrict__ B4, const u8* __restrict__ BS,
    const float* __restrict__ bias, float* __restrict__ C,
    int M, int N, int K)
{
    __shared__ __align__(16) u8 smem[2 * BUF_BYTES];   // 34 KB -> 4 blocks/CU

    const int tid  = threadIdx.x;
    const int wave = tid >> 6;
    const int lane = tid & 63;
    const int l31  = lane & 31;
    const int lhi  = lane >> 5;
    const int wm   = wave >> 1;
    const int wn   = wave & 1;
    const int ntk  = K >> 7;

    // XCD-chunked + L2-grouped block ordering (8 bm-panels + streamed B per XCD)
    const int nbn = N >> 7;
    const int nbm = M >> 7;
    int nwg = gridDim.x;
    int bid = blockIdx.x;
    int bm, bn;
    if ((nwg & 7) == 0 && (nbm & 7) == 0) {
        int cpx = nwg >> 3;
        int wg  = (bid & 7) * cpx + (bid >> 3);
        int bpc = nbm >> 3;
        int c   = wg / cpx;
        int r   = wg - c * cpx;
        bm = c * bpc + (r & 7);
        bn = r >> 3;
    } else {
        bn = bid % nbn;
        bm = bid / nbn;
    }

    v16f acc[2][2];
#pragma unroll
    for (int i = 0; i < 2; ++i)
#pragma unroll
        for (int j = 0; j < 2; ++j)
#pragma unroll
            for (int r = 0; r < 16; ++r) acc[i][j][r] = 0.f;

    // per-wave staging constants (all linear/contiguous)
    const int dataLdsOfs = wave * 2048;                 // 2 x 1KB per wave
    const int scLdsOfs   = ((wave < 2) ? 16384 : 16896) + (wave & 1) * 256;

#define STAGE(bufofs, kt)                                                     \
    do {                                                                      \
        const u8* ab_ = A4 + ((size_t)(bm * ntk + (kt))) * 8192 + dataLdsOfs; \
        const u8* bb_ = B4 + ((size_t)(bn * ntk + (kt))) * 8192 + dataLdsOfs; \
        gload16(ab_ + lane * 16,        smem + (bufofs) + dataLdsOfs);        \
        gload16(ab_ + 1024 + lane * 16, smem + (bufofs) + dataLdsOfs + 1024); \
        gload16(bb_ + lane * 16,        smem + (bufofs) + 8192 + dataLdsOfs); \
        gload16(bb_ + 1024 + lane * 16,                                       \
                smem + (bufofs) + 8192 + dataLdsOfs + 1024);                  \
        const u8* sb_ = ((wave < 2)                                           \
                ? AS + ((size_t)(bm * ntk + (kt))) * 512                      \
                : BS + ((size_t)(bn * ntk + (kt))) * 512)                     \
            + (wave & 1) * 256;                                               \
        gload4(sb_ + lane * 4, smem + (bufofs) + scLdsOfs);                   \
    } while (0)

#define COMPUTE(cofs)                                                         \
    do {                                                                      \
        const u32* Asc_ = (const u32*)(smem + (cofs) + 16384);                \
        const u32* Bsc_ = (const u32*)(smem + (cofs) + 16896);                \
        u32 sa32[2], sb32[2];                                                 \
        sa32[0] = Asc_[wm * 64 + l31];      sa32[1] = Asc_[wm * 64 + 32 + l31];\
        sb32[0] = Bsc_[wn * 64 + l31];      sb32[1] = Bsc_[wn * 64 + 32 + l31];\
        _Pragma("unroll")                                                     \
        for (int ks = 0; ks < 2; ++ks) {                                      \
            const int s_  = ks * 2 + lhi;                                     \
            const int sh_ = s_ * 8;                                           \
            v8i a_[2], b_[2];                                                 \
            _Pragma("unroll")                                                 \
            for (int mi = 0; mi < 2; ++mi) {                                  \
                v4i t_ = *(const v4i*)(smem + (cofs) + s_ * 2048              \
                                       + (wm * 64 + mi * 32 + l31) * 16);     \
                a_[mi][0] = t_[0]; a_[mi][1] = t_[1];                         \
                a_[mi][2] = t_[2]; a_[mi][3] = t_[3];                         \
                a_[mi][4] = 0; a_[mi][5] = 0; a_[mi][6] = 0; a_[mi][7] = 0;   \
            }                                                                 \
            _Pragma("unroll")                                                 \
            for (int ni = 0; ni < 2; ++ni) {                                  \
                v4i t_ = *(const v4i*)(smem + (cofs) + 8192 + s_ * 2048       \
                                       + (wn * 64 + ni * 32 + l31) * 16);     \
                b_[ni][0] = t_[0]; b_[ni][1] = t_[1];                         \
                b_[ni][2] = t_[2]; b_[ni][3] = t_[3];                         \
                b_[ni][4] = 0; b_[ni][5] = 0; b_[ni][6] = 0; b_[ni][7] = 0;   \
            }                                                                 \
            _Pragma("unroll")                                                 \
            for (int mi = 0; mi < 2; ++mi) {                                  \
                int sA_ = (int)((sa32[mi] >> sh_) & 0xffu);                   \
                _Pragma("unroll")                                             \
                for (int ni = 0; ni < 2; ++ni) {                              \
                    int sB_ = (int)((sb32[ni] >> sh_) & 0xffu);               \
                    acc[mi][ni] = __builtin_amdgcn_mfma_scale_f32_32x32x64_f8f6f4(\
                        a_[mi], b_[ni], acc[mi][ni], 4, 4, 0, sA_, 0, sB_);   \
                }                                                             \
            }                                                                 \
        }                                                                     \
    } while (0)

    const int NT = K >> 7;

    STAGE(0, 0);
    for (int t = 0; t < NT - 1; ++t) {
        const int pofs = ((t + 1) & 1) * BUF_BYTES;
        STAGE(pofs, t + 1);
        asm volatile("s_waitcnt vmcnt(5)" ::: "memory");  // tile t landed; t+1 in flight
        __builtin_amdgcn_s_barrier();
        COMPUTE((t & 1) * BUF_BYTES);
        __builtin_amdgcn_s_barrier();   // all waves done reading before re-stage
    }
    asm volatile("s_waitcnt vmcnt(0)" ::: "memory");      // drain last tile
    __builtin_amdgcn_s_barrier();
    COMPUTE(((NT - 1) & 1) * BUF_BYTES);

    // Epilogue: 32x32 C/D: col = lane&31, row = (reg&3)+8*(reg>>2)+4*(lane>>5)
    const int cb = bn * 128 + wn * 64;
    const int rb = bm * 128 + wm * 64;
#pragma unroll
    for (int ni = 0; ni < 2; ++ni) {
        float bb = bias[cb + ni * 32 + l31];
#pragma unroll
        for (int mi = 0; mi < 2; ++mi) {
#pragma unroll
            for (int reg = 0; reg < 16; ++reg) {
                int row = (reg & 3) + 8 * (reg >> 2) + 4 * lhi;
                C[(size_t)(rb + mi * 32 + row) * N + cb + ni * 32 + l31]
                    = acc[mi][ni][reg] + bb;
            }
        }
    }
#undef STAGE
#undef COMPUTE
}

// ---------------------------------------------------------------------------
extern "C" void kernel_launch(void* const* d_in, const int* in_sizes, int n_in,
                              void* d_out, int out_size, void* d_ws, size_t ws_size,
                              hipStream_t stream)
{
    const float* x    = (const float*)d_in[0];   // [M, K] = [8192, 4096]
    const float* w    = (const float*)d_in[1];   // [O, K] = [16384, 4096]
    const float* bias = (const float*)d_in[2];   // [O]

    const int O = in_sizes[2];            // 16384
    const int K = in_sizes[1] / O;        // 4096
    const int M = in_sizes[0] / K;        // 8192

    u8* x4 = (u8*)d_ws;                           // [M, K/2]  tiled
    u8* w4 = x4 + (size_t)M * (K / 2);            // [O, K/2]  tiled
    u8* xs = w4 + (size_t)O * (K / 2);            // [M, K/32] tiled
    u8* ws = xs + (size_t)M * (K / 32);           // [O, K/32] tiled

    const int gpr = K / 32;
    const int ntk = K / 128;
    const int gx = M * gpr;
    const int gw = O * gpr;
    rotquant4_kernel<<<(gx + 255) / 256, 256, 0, stream>>>(x, x4, xs, gx, gpr, ntk);
    rotquant4_kernel<<<(gw + 255) / 256, 256, 0, stream>>>(w, w4, ws, gw, gpr, ntk);

    dim3 grid((M / 128) * (O / 128));     // 8192 blocks
    gemm4_bias<<<grid, 256, 0, stream>>>(x4, xs, w4, ws, bias, (float*)d_out,
                                         M, O, K);
}

// Round 5
// 492.958 us; speedup vs baseline: 2.9168x; 1.0579x over previous
//
#include <hip/hip_runtime.h>

typedef unsigned short u16;
typedef unsigned int u32;
typedef unsigned char u8;
typedef int v8i __attribute__((ext_vector_type(8)));
typedef int v4i __attribute__((ext_vector_type(4)));
typedef float v16f __attribute__((ext_vector_type(16)));

#define INV_SQRT32 0.17677669529663688f

// ---------------------------------------------------------------------------
// Stage 1: per-32-group FWHT (Sylvester Hadamard) + MXFP4 quantize.
// Output is written PRE-TILED for the GEMM (tile = 128 rows x 128 k):
//   data  chunk16 for (row, kblock kb):  tile = (row>>7)*ntk + (kb>>2)
//         byte = tile*8192 + (kb&3)*2048 + (row&127)*16     (slot-major)
//   scale byte for (row, kb):  tile*512 + (row&127)*4 + (kb&3)
// UNCHANGED from round 4.
// ---------------------------------------------------------------------------
__global__ __launch_bounds__(256) void rotquant4_kernel(
    const float* __restrict__ T, u8* __restrict__ Q4, u8* __restrict__ S,
    int ngroups, int gpr /* K/32 */, int ntk /* K/128 */)
{
    int g = blockIdx.x * 256 + threadIdx.x;
    if (g >= ngroups) return;

    int row = g / gpr;
    int kb  = g - row * gpr;

    const float4* src = (const float4*)(T + (size_t)g * 32);
    float v[32];
#pragma unroll
    for (int i = 0; i < 8; ++i) {
        float4 t = src[i];
        v[i*4+0] = t.x; v[i*4+1] = t.y; v[i*4+2] = t.z; v[i*4+3] = t.w;
    }

#pragma unroll
    for (int s = 1; s < 32; s <<= 1) {
#pragma unroll
        for (int i = 0; i < 32; ++i) {
            if (!(i & s)) {
                float a = v[i], b = v[i | s];
                v[i] = a + b;
                v[i | s] = a - b;
            }
        }
    }

    float amax = 0.f;
#pragma unroll
    for (int i = 0; i < 32; ++i) {
        v[i] *= INV_SQRT32;
        amax = fmaxf(amax, fabsf(v[i]));
    }

    u32 ab = __float_as_uint(amax);
    int be = (int)(ab >> 23);
    u32 w[4] = {0u, 0u, 0u, 0u};
    u8 sbyte = 0;
    if (be >= 3) {
        sbyte = (u8)(be - 2);               // E8M0 of 2^(be-129)
        float iscale = __uint_as_float((u32)(256 - be) << 23); // 2^(129-be)
#pragma unroll
        for (int i = 0; i < 32; ++i) {
            float a = v[i] * iscale;        // exact
            float m = fminf(fabsf(a), 6.0f);
            int c = (m < 0.25f) ? 0 :
                    (m < 0.75f) ? 1 :
                    (m < 1.25f) ? 2 :
                    (m < 1.75f) ? 3 :
                    (m < 2.5f)  ? 4 :
                    (m < 3.5f)  ? 5 :
                    (m < 5.0f)  ? 6 : 7;
            c |= (int)((__float_as_uint(a) >> 28) & 8u);
            w[i >> 3] |= (u32)c << (4 * (i & 7));
        }
    }

    size_t tile = (size_t)(row >> 7) * (size_t)ntk + (size_t)(kb >> 2);
    uint4 p; p.x = w[0]; p.y = w[1]; p.z = w[2]; p.w = w[3];
    *(uint4*)(Q4 + tile * 8192 + (size_t)(kb & 3) * 2048
              + (size_t)(row & 127) * 16) = p;
    S[tile * 512 + (size_t)(row & 127) * 4 + (kb & 3)] = sbyte;
}

// ---------------------------------------------------------------------------
// Stage 2: C = deq(A) * deq(B)^T + bias via MX-scaled FP4 MFMA.
// BM=256, BN=128, BK=128. 4 waves (2x2), per-wave 128x64 output (4x2
// reg-blocking, 16 MFMA / K-tile / wave). Validated 2-phase counted-vmcnt
// loop (8 uniform loads/wave/stage, vmcnt(8)). LDS per buffer:
//   A data [half2][slot4][row128][16B]  @0      (16 KB)
//   B data [slot4][row128][16B]         @16384  (8 KB)
//   A scales [row256][4B]               @24576  (1 KB)
//   B scales [row128][4B] (+512 dup)    @25600  (1 KB)
// ---------------------------------------------------------------------------
__device__ __forceinline__ void gload16(const void* g, void* l)
{
    __builtin_amdgcn_global_load_lds(
        (__attribute__((address_space(1))) void*)g,
        (__attribute__((address_space(3))) void*)l, 16, 0, 0);
}

#define BUF_BYTES 26624

__global__ __launch_bounds__(256, 2) void gemm4_bias(
    const u8* __restrict__ A4, const u8* __restrict__ AS,
    const u8* __restrict__ B4, const u8* __restrict__ BS,
    const float* __restrict__ bias, float* __restrict__ C,
    int M, int N, int K)
{
    __shared__ __align__(16) u8 smem[2 * BUF_BYTES];   // 53248 B

    const int tid  = threadIdx.x;
    const int wave = tid >> 6;
    const int lane = tid & 63;
    const int l31  = lane & 31;
    const int lhi  = lane >> 5;
    const int wm   = wave >> 1;   // 2x2 wave grid over 256x128 tile
    const int wn   = wave & 1;
    const int ntk  = K >> 7;

    // XCD-chunked + L2-grouped block ordering
    const int nbn = N >> 7;       // 128-col tiles
    const int nbm = M >> 8;       // 256-row tiles
    int nwg = gridDim.x;
    int bid = blockIdx.x;
    int bm, bn;
    if ((nwg & 7) == 0 && (nbm & 7) == 0) {
        int cpx = nwg >> 3;
        int c   = bid & 7;                 // XCD
        int r   = bid >> 3;                // [0, cpx)
        int bpc = nbm >> 3;                // bm-panels per chunk (pow2)
        int lb  = __builtin_ctz(bpc);
        bm = c * bpc + (r & (bpc - 1));
        bn = r >> lb;
        (void)cpx;
    } else {
        bn = bid % nbn;
        bm = bid / nbn;
    }

    v16f acc[4][2];
#pragma unroll
    for (int i = 0; i < 4; ++i)
#pragma unroll
        for (int j = 0; j < 2; ++j)
#pragma unroll
            for (int r = 0; r < 16; ++r) acc[i][j][r] = 0.f;

    // ---- staging sources (per-wave constants except kt)
    // A data: wave w covers bytes [w*4096, w*4096+4096) of concat(tile0,tile1)
    const size_t aTile0 = (size_t)(2 * bm + (wave >> 1)) * ntk;   // tile row-half
    const int    aSub   = (wave & 1) * 4096;
    const size_t bTile0 = (size_t)bn * ntk;
    // A scales: per-lane split across the two row-halves
    const size_t asTile = (size_t)(2 * bm + (lane >> 5)) * ntk;
    const int    asOfs  = (lane & 31) * 16 - lane * 16;  // lane-relative fix
    // B scales: lanes 32-63 duplicate lanes 0-31
    const int    bsOfs  = (lane & 31) * 16 - lane * 16;

#define STAGE(bufofs, kt)                                                     \
    do {                                                                      \
        const u8* at_ = A4 + (aTile0 + (kt)) * 8192 + aSub + lane * 16;       \
        const u8* bt_ = B4 + (bTile0 + (kt)) * 8192 + wave * 2048 + lane * 16;\
        _Pragma("unroll")                                                     \
        for (int j = 0; j < 4; ++j)                                           \
            gload16(at_ + j * 1024,                                           \
                    smem + (bufofs) + wave * 4096 + j * 1024);                \
        _Pragma("unroll")                                                     \
        for (int j = 0; j < 2; ++j)                                           \
            gload16(bt_ + j * 1024,                                           \
                    smem + (bufofs) + 16384 + wave * 2048 + j * 1024);        \
        gload16(AS + (asTile + (kt)) * 512 + lane * 16 + asOfs,               \
                smem + (bufofs) + 24576);                                     \
        gload16(BS + (bTile0 + (kt)) * 512 + lane * 16 + bsOfs,               \
                smem + (bufofs) + 25600);                                     \
    } while (0)

#define COMPUTE(cofs)                                                         \
    do {                                                                      \
        u32 sa_[4], sb_[2];                                                   \
        _Pragma("unroll")                                                     \
        for (int mi = 0; mi < 4; ++mi)                                        \
            sa_[mi] = *(const u32*)(smem + (cofs) + 24576                     \
                                    + (wm * 128 + mi * 32 + l31) * 4);        \
        _Pragma("unroll")                                                     \
        for (int ni = 0; ni < 2; ++ni)                                        \
            sb_[ni] = *(const u32*)(smem + (cofs) + 25600                     \
                                    + (wn * 64 + ni * 32 + l31) * 4);        \
        _Pragma("unroll")                                                     \
        for (int ks = 0; ks < 2; ++ks) {                                      \
            const int s_  = ks * 2 + lhi;                                     \
            const int sh_ = s_ * 8;                                           \
            v8i af_[4], bf_[2];                                               \
            _Pragma("unroll")                                                 \
            for (int mi = 0; mi < 4; ++mi) {                                  \
                v4i t_ = *(const v4i*)(smem + (cofs) + wm * 8192 + s_ * 2048  \
                                       + (mi * 32 + l31) * 16);               \
                af_[mi] = __builtin_shufflevector(t_, t_, 0,1,2,3,-1,-1,-1,-1);\
            }                                                                 \
            _Pragma("unroll")                                                 \
            for (int ni = 0; ni < 2; ++ni) {                                  \
                v4i t_ = *(const v4i*)(smem + (cofs) + 16384 + s_ * 2048      \
                                       + (wn * 64 + ni * 32 + l31) * 16);     \
                bf_[ni] = __builtin_shufflevector(t_, t_, 0,1,2,3,-1,-1,-1,-1);\
            }                                                                 \
            _Pragma("unroll")                                                 \
            for (int mi = 0; mi < 4; ++mi) {                                  \
                int sA_ = (int)((sa_[mi] >> sh_) & 0xffu);                    \
                _Pragma("unroll")                                             \
                for (int ni = 0; ni < 2; ++ni) {                              \
                    int sB_ = (int)((sb_[ni] >> sh_) & 0xffu);                \
                    acc[mi][ni] = __builtin_amdgcn_mfma_scale_f32_32x32x64_f8f6f4(\
                        af_[mi], bf_[ni], acc[mi][ni], 4, 4, 0, sA_, 0, sB_); \
                }                                                             \
            }                                                                 \
        }                                                                     \
    } while (0)

    const int NT = K >> 7;

    STAGE(0, 0);
    for (int t = 0; t < NT - 1; ++t) {
        const int pofs = ((t + 1) & 1) * BUF_BYTES;
        STAGE(pofs, t + 1);
        asm volatile("s_waitcnt vmcnt(8)" ::: "memory");  // tile t landed; t+1 in flight
        __builtin_amdgcn_s_barrier();
        asm volatile("" ::: "memory");
        COMPUTE((t & 1) * BUF_BYTES);
        __builtin_amdgcn_s_barrier();   // all waves done reading before re-stage
        asm volatile("" ::: "memory");
    }
    asm volatile("s_waitcnt vmcnt(0)" ::: "memory");      // drain last tile
    __builtin_amdgcn_s_barrier();
    asm volatile("" ::: "memory");
    COMPUTE(((NT - 1) & 1) * BUF_BYTES);

    // Epilogue: 32x32 C/D: col = lane&31, row = (reg&3)+8*(reg>>2)+4*(lane>>5)
    const int cb = bn * 128 + wn * 64;
    const int rb = bm * 256 + wm * 128;
#pragma unroll
    for (int ni = 0; ni < 2; ++ni) {
        float bb = bias[cb + ni * 32 + l31];
#pragma unroll
        for (int mi = 0; mi < 4; ++mi) {
#pragma unroll
            for (int reg = 0; reg < 16; ++reg) {
                int row = (reg & 3) + 8 * (reg >> 2) + 4 * lhi;
                C[(size_t)(rb + mi * 32 + row) * N + cb + ni * 32 + l31]
                    = acc[mi][ni][reg] + bb;
            }
        }
    }
#undef STAGE
#undef COMPUTE
}

// ---------------------------------------------------------------------------
extern "C" void kernel_launch(void* const* d_in, const int* in_sizes, int n_in,
                              void* d_out, int out_size, void* d_ws, size_t ws_size,
                              hipStream_t stream)
{
    const float* x    = (const float*)d_in[0];   // [M, K] = [8192, 4096]
    const float* w    = (const float*)d_in[1];   // [O, K] = [16384, 4096]
    const float* bias = (const float*)d_in[2];   // [O]

    const int O = in_sizes[2];            // 16384
    const int K = in_sizes[1] / O;        // 4096
    const int M = in_sizes[0] / K;        // 8192

    u8* x4 = (u8*)d_ws;                           // [M, K/2]  tiled
    u8* w4 = x4 + (size_t)M * (K / 2);            // [O, K/2]  tiled
    u8* xs = w4 + (size_t)O * (K / 2);            // [M, K/32] tiled
    u8* ws = xs + (size_t)M * (K / 32);           // [O, K/32] tiled

    const int gpr = K / 32;
    const int ntk = K / 128;
    const int gx = M * gpr;
    const int gw = O * gpr;
    rotquant4_kernel<<<(gx + 255) / 256, 256, 0, stream>>>(x, x4, xs, gx, gpr, ntk);
    rotquant4_kernel<<<(gw + 255) / 256, 256, 0, stream>>>(w, w4, ws, gw, gpr, ntk);

    dim3 grid((M / 256) * (O / 128));     // 4096 blocks
    gemm4_bias<<<grid, 256, 0, stream>>>(x4, xs, w4, ws, bias, (float*)d_out,
                                         M, O, K);
}